// Round 2
// baseline (104.661 us; speedup 1.0000x reference)
//
#include <hip/hip_runtime.h>

// Chamfer distance, B=8, N=M=8192, D=3, fp32 — R13: prepacked frags + LDS
// broadcast, 2-phase double-buffered global_load_lds pipeline.
//
// dist[i][j] = nx_i + ny_j - 2 x_i.y_j; out = mean(min_j) + mean(min_i).
// K=16 bf16-split packing (validated R8-R12, absmax 0.0):
//   A row = [ah0 ah1 ah2 ah0 ah1 ah2 al0 al1 | al2 nxh nxl 1 1 0 0 0]
//   B col = [yh0 yh1 yh2 yl0 yl1 yl2 yh0 yh1 | yh2 1 1 nyh nyl 0 0 0]
//
// R12 analysis: MFMA busy time == 13.8us floor but MfmaUtil only 30% —
// latency-bound: 4 waves/block each streamed the SAME B tiles from L2
// (512MB, dependent ~200cy loads, no prefetch depth). R13: stage prepacked
// tiles once per block into LDS via global_load_lds (width 16, no VGPR
// round-trip, no build VALU), 16KB chunks double-buffered (32KB LDS ->
// still 3 blocks/CU). Per phase ~3100 MFMA-cyc/CU vs ~500cy load latency:
// the per-chunk vmcnt drain is nearly free. L2 traffic 4x down.

#define B_ 8
#define N_ 8192
#define PTS (B_ * N_)            // 65536 points per cloud
#define ROWS_TOTAL (2 * PTS)     // 131072 row-min slots (both directions)
#define NTILES 2048              // 32-point tiles per cloud (65536/32)
#define TPB 256
#define CHUNK 16                 // B-tiles per LDS chunk (16KB)

typedef short bf16x8 __attribute__((ext_vector_type(8)));
typedef float f32x16 __attribute__((ext_vector_type(16)));

__device__ __forceinline__ unsigned b16(float f) {   // fp32 -> bf16 bits (RNE)
  unsigned u = __float_as_uint(f);
  return (u + 0x7FFFu + ((u >> 16) & 1u)) >> 16;
}
__device__ __forceinline__ float bf(unsigned h) { return __uint_as_float(h << 16); }

// ---- one-shot fragment packing: 262144 tasks (A/B x dir x 65536 points) ----
__global__ __launch_bounds__(256) void pack_frags_k(
    const float* __restrict__ x, const float* __restrict__ y,
    uint4* __restrict__ afrag, uint4* __restrict__ bfrag) {
  const unsigned one = 0x3F80u;
  int t = blockIdx.x * 256 + threadIdx.x;   // 0 .. 262143
  int kind = t >> 17;                        // 0 = A-frag, 1 = B-frag
  int dir = (t >> 16) & 1;                   // 0: rows=x scan y; 1: rows=y scan x
  int p = t & 65535;
  int tile = dir * NTILES + (p >> 5), m = p & 31;
  if (kind == 0) {
    const float* src = dir ? y : x;          // row ("own") cloud
    const float* po = src + 3 * p;
    float v0 = po[0], v1 = po[1], v2 = po[2];
    float nv = fmaf(v0, v0, fmaf(v1, v1, v2 * v2));
    float a0 = -2.0f * v0, a1 = -2.0f * v1, a2 = -2.0f * v2;
    unsigned ah0 = b16(a0), ah1 = b16(a1), ah2 = b16(a2);
    unsigned al0 = b16(a0 - bf(ah0)), al1 = b16(a1 - bf(ah1)), al2 = b16(a2 - bf(ah2));
    unsigned nh = b16(nv), nl = b16(nv - bf(nh));
    afrag[tile * 64 + m]      = make_uint4(ah0 | (ah1 << 16), ah2 | (ah0 << 16),
                                           ah1 | (ah2 << 16), al0 | (al1 << 16));
    afrag[tile * 64 + 32 + m] = make_uint4(al2 | (nh << 16), nl | (one << 16), one, 0u);
  } else {
    const float* src = dir ? x : y;          // candidate cloud
    const float* pc = src + 3 * p;
    float c0 = pc[0], c1 = pc[1], c2 = pc[2];
    float nc = fmaf(c0, c0, fmaf(c1, c1, c2 * c2));
    unsigned yh0 = b16(c0), yh1 = b16(c1), yh2 = b16(c2);
    unsigned yl0 = b16(c0 - bf(yh0)), yl1 = b16(c1 - bf(yh1)), yl2 = b16(c2 - bf(yh2));
    unsigned nh = b16(nc), nl = b16(nc - bf(nh));
    bfrag[tile * 64 + m]      = make_uint4(yh0 | (yh1 << 16), yh2 | (yl0 << 16),
                                           yl1 | (yl2 << 16), yh0 | (yh1 << 16));
    bfrag[tile * 64 + 32 + m] = make_uint4(yh2 | (one << 16), one | (nh << 16), nl, 0u);
  }
}

// wave w stages tiles [w*4 .. w*4+3] of a 16-tile chunk: 4 x global_load_lds,
// each writes 64 lanes x 16B = 1KB contiguous (linear dest, linear src).
__device__ __forceinline__ void stage_chunk(uint4* dst, const uint4* src,
                                            int w, int lane) {
#pragma unroll
  for (int k = 0; k < 4; ++k) {
    int tile = w * 4 + k;
    const uint4* g = src + tile * 64 + lane;   // per-lane global address
    uint4* l = dst + tile * 64;                // wave-uniform LDS base
    __builtin_amdgcn_global_load_lds(
        (const __attribute__((address_space(1))) unsigned int*)g,
        (__attribute__((address_space(3))) unsigned int*)l, 16, 0, 0);
  }
}

// ---- main: 2048 blocks x 256 thr; block = 4 waves x 64 rows = 256 rows,
// scans one candidate quarter (2048 cands = 64 prepacked tiles). ----
__global__ __launch_bounds__(TPB, 3) void chamfer_main_k(
    const uint4* __restrict__ afrag, const uint4* __restrict__ bfrag,
    float* __restrict__ gpart) {
  __shared__ uint4 ldsB[2][CHUNK * 64];        // 2 x 16KB double buffer

  int t = threadIdx.x, lane = t & 63, w = t >> 6;    // 4 waves
  int b0 = blockIdx.x;
  // XCD-bijective swizzle (2048 % 8 == 0): each XCD gets 256 consecutive
  // effective ids = 2 full (dir,batch) families -> small hot L2 set.
  int eff = ((b0 & 7) << 8) | (b0 >> 3);
  int q = eff & 3;                 // candidate quarter (64 B-tiles)
  int rg = eff >> 2;               // 0..511 : 256-row groups
  int dir = rg >> 8;
  int batch = (rg >> 5) & 7;
  int rb = rg & 31;                // 256-row block within batch

  // A-frags: 2 row-tiles (64 rows) per wave, straight from prepacked global.
  int tileA0 = dir * NTILES + batch * 256 + rb * 8 + w * 2;
  bf16x8 A0 = __builtin_bit_cast(bf16x8, afrag[tileA0 * 64 + lane]);
  bf16x8 A1 = __builtin_bit_cast(bf16x8, afrag[(tileA0 + 1) * 64 + lane]);

  const uint4* btile = bfrag + (size_t)(dir * NTILES + batch * 256 + q * 64) * 64;

  f32x16 z, rm0, rm1;
#pragma unroll
  for (int r = 0; r < 16; ++r) { z[r] = 0.0f; rm0[r] = 1e30f; rm1[r] = 1e30f; }

  stage_chunk(ldsB[0], btile, w, lane);        // prologue: chunk 0
  __syncthreads();                             // drains vmcnt

  for (int ch = 0; ch < 4; ++ch) {             // 4 chunks of 16 tiles
    if (ch < 3)                                // issue next chunk's loads first
      stage_chunk(ldsB[(ch + 1) & 1], btile + (ch + 1) * CHUNK * 64, w, lane);

    const uint4* cur = ldsB[ch & 1];
#pragma unroll 2
    for (int i = 0; i < 8; ++i) {              // 16 tiles, 2 per iter
      bf16x8 B0 = __builtin_bit_cast(bf16x8, cur[(2 * i) * 64 + lane]);
      bf16x8 B1 = __builtin_bit_cast(bf16x8, cur[(2 * i + 1) * 64 + lane]);
      f32x16 acc0 = __builtin_amdgcn_mfma_f32_32x32x16_bf16(A0, B0, z, 0, 0, 0);
      f32x16 acc1 = __builtin_amdgcn_mfma_f32_32x32x16_bf16(A1, B0, z, 0, 0, 0);
      f32x16 acc2 = __builtin_amdgcn_mfma_f32_32x32x16_bf16(A0, B1, z, 0, 0, 0);
      f32x16 acc3 = __builtin_amdgcn_mfma_f32_32x32x16_bf16(A1, B1, z, 0, 0, 0);
#pragma unroll
      for (int r = 0; r < 16; ++r) {
        rm0[r] = fminf(fminf(rm0[r], acc0[r]), acc2[r]);   // v_min3_f32
        rm1[r] = fminf(fminf(rm1[r], acc1[r]), acc3[r]);   // v_min3_f32
      }
    }
    __syncthreads();                           // drains next chunk's vmcnt too
  }

  // ---- epilogue: fold 32 cols per half (butterfly), store row-mins ----
#pragma unroll
  for (int msk = 1; msk <= 16; msk <<= 1)
#pragma unroll
    for (int r = 0; r < 16; ++r) {
      rm0[r] = fminf(rm0[r], __shfl_xor(rm0[r], msk, 64));
      rm1[r] = fminf(rm1[r], __shfl_xor(rm1[r], msk, 64));
    }

  int rowbase = dir * PTS + batch * N_ + rb * 256 + w * 64;
  float* gp = gpart + q * ROWS_TOTAL + rowbase;
  if ((lane & 31) == 0) {                      // lanes 0 and 32 (h = lane>>5)
    int h = lane >> 5;
#pragma unroll
    for (int r = 0; r < 16; ++r) {
      int rr = (r & 3) + 8 * (r >> 2) + 4 * h;
      gp[rr] = rm0[r];
      gp[32 + rr] = rm1[r];
    }
  }
}

// ---- final: min the 4 candidate-quarter partials, sum everything ----
__global__ __launch_bounds__(256) void chamfer_final_k(
    const float* __restrict__ gpart, float* __restrict__ out) {
  int i = blockIdx.x * 256 + threadIdx.x;    // 32768 threads x 4 rows (float4)
  const float4* g4 = reinterpret_cast<const float4*>(gpart);
  float4 a = g4[i];
  float4 b = g4[i + (ROWS_TOTAL / 4)];
  float4 c = g4[i + 2 * (ROWS_TOTAL / 4)];
  float4 d = g4[i + 3 * (ROWS_TOTAL / 4)];
  float s = fminf(fminf(a.x, b.x), fminf(c.x, d.x))
          + fminf(fminf(a.y, b.y), fminf(c.y, d.y))
          + fminf(fminf(a.z, b.z), fminf(c.z, d.z))
          + fminf(fminf(a.w, b.w), fminf(c.w, d.w));
  for (int off = 32; off > 0; off >>= 1) s += __shfl_down(s, off, 64);
  __shared__ float red[4];
  int lane = threadIdx.x & 63, wv = threadIdx.x >> 6;
  if (lane == 0) red[wv] = s;
  __syncthreads();
  if (threadIdx.x == 0) {
    float tt = (red[0] + red[1]) + (red[2] + red[3]);
    atomicAdd(out, tt * (1.0f / (float)PTS));
  }
}

extern "C" void kernel_launch(void* const* d_in, const int* in_sizes, int n_in,
                              void* d_out, int out_size, void* d_ws, size_t ws_size,
                              hipStream_t stream) {
  const float* x = (const float*)d_in[0];
  const float* y = (const float*)d_in[1];
  float* out = (float*)d_out;
  // ws layout: gpart 2MB | afrag 4MB | bfrag 4MB  (10MB total)
  float* gpart = (float*)d_ws;
  uint4* afrag = (uint4*)((char*)d_ws + (size_t)4 * ROWS_TOTAL * sizeof(float));
  uint4* bfrag = afrag + (size_t)2 * NTILES * 64;

  hipMemsetAsync(out, 0, sizeof(float), stream);
  pack_frags_k<<<1024, 256, 0, stream>>>(x, y, afrag, bfrag);
  chamfer_main_k<<<2048, TPB, 0, stream>>>(afrag, bfrag, gpart);
  chamfer_final_k<<<128, 256, 0, stream>>>(gpart, out);
}

// Round 3
// 102.970 us; speedup vs baseline: 1.0164x; 1.0164x over previous
//
#include <hip/hip_runtime.h>

// Chamfer distance, B=8, N=M=8192, D=3, fp32 — R14: barrier-free streaming
// + explicit 2-ahead register prefetch of B tiles.
//
// dist[i][j] = nx_i + ny_j - 2 x_i.y_j; out = mean(min_j) + mean(min_i).
// K=16 bf16-split packing (validated R8-R13, absmax 0.0):
//   A row = [ah0 ah1 ah2 ah0 ah1 ah2 al0 al1 | al2 nxh nxl 1 1 0 0 0]
//   B col = [yh0 yh1 yh2 yl0 yl1 yl2 yh0 yh1 | yh2 1 1 nyh nyl 0 0 0]
//
// R11-R13 all ~42-48us with MfmaUtil*dur == 13.8us MFMA floor exactly:
// latency-bound, not pipe-bound. R12 (barrier-free) exposed ~250cy of
// dependent L2 load latency per 2-tile step (~440cy/step, duty 29%).
// R14: same structure, but tiles for step j+2 are loaded into registers
// while step j computes (manual 4-reg rotation, unroll 4 -> renaming;
// uniform offsets keep address math scalar). Per-wave matrix duty ~60%,
// x3 waves/SIMD -> matrix pipe saturation regime.

#define B_ 8
#define N_ 8192
#define PTS (B_ * N_)            // 65536 points per cloud
#define ROWS_TOTAL (2 * PTS)     // 131072 row-min slots (both directions)
#define NTILES 2048              // 32-point tiles per cloud (65536/32)
#define TPB 256

typedef short bf16x8 __attribute__((ext_vector_type(8)));
typedef float f32x16 __attribute__((ext_vector_type(16)));

__device__ __forceinline__ unsigned b16(float f) {   // fp32 -> bf16 bits (RNE)
  unsigned u = __float_as_uint(f);
  return (u + 0x7FFFu + ((u >> 16) & 1u)) >> 16;
}
__device__ __forceinline__ float bf(unsigned h) { return __uint_as_float(h << 16); }

// ---- one-shot fragment packing: 262144 tasks (A/B x dir x 65536 points) ----
__global__ __launch_bounds__(256) void pack_frags_k(
    const float* __restrict__ x, const float* __restrict__ y,
    uint4* __restrict__ afrag, uint4* __restrict__ bfrag) {
  const unsigned one = 0x3F80u;
  int t = blockIdx.x * 256 + threadIdx.x;   // 0 .. 262143
  int kind = t >> 17;                        // 0 = A-frag, 1 = B-frag
  int dir = (t >> 16) & 1;                   // 0: rows=x scan y; 1: rows=y scan x
  int p = t & 65535;
  int tile = dir * NTILES + (p >> 5), m = p & 31;
  if (kind == 0) {
    const float* src = dir ? y : x;          // row ("own") cloud
    const float* po = src + 3 * p;
    float v0 = po[0], v1 = po[1], v2 = po[2];
    float nv = fmaf(v0, v0, fmaf(v1, v1, v2 * v2));
    float a0 = -2.0f * v0, a1 = -2.0f * v1, a2 = -2.0f * v2;
    unsigned ah0 = b16(a0), ah1 = b16(a1), ah2 = b16(a2);
    unsigned al0 = b16(a0 - bf(ah0)), al1 = b16(a1 - bf(ah1)), al2 = b16(a2 - bf(ah2));
    unsigned nh = b16(nv), nl = b16(nv - bf(nh));
    afrag[tile * 64 + m]      = make_uint4(ah0 | (ah1 << 16), ah2 | (ah0 << 16),
                                           ah1 | (ah2 << 16), al0 | (al1 << 16));
    afrag[tile * 64 + 32 + m] = make_uint4(al2 | (nh << 16), nl | (one << 16), one, 0u);
  } else {
    const float* src = dir ? x : y;          // candidate cloud
    const float* pc = src + 3 * p;
    float c0 = pc[0], c1 = pc[1], c2 = pc[2];
    float nc = fmaf(c0, c0, fmaf(c1, c1, c2 * c2));
    unsigned yh0 = b16(c0), yh1 = b16(c1), yh2 = b16(c2);
    unsigned yl0 = b16(c0 - bf(yh0)), yl1 = b16(c1 - bf(yh1)), yl2 = b16(c2 - bf(yh2));
    unsigned nh = b16(nc), nl = b16(nc - bf(nh));
    bfrag[tile * 64 + m]      = make_uint4(yh0 | (yh1 << 16), yh2 | (yl0 << 16),
                                           yl1 | (yl2 << 16), yh0 | (yh1 << 16));
    bfrag[tile * 64 + 32 + m] = make_uint4(yh2 | (one << 16), one | (nh << 16), nl, 0u);
  }
}

// ---- main: 2048 blocks x 256 thr; no LDS, no barriers ----
// block = 4 waves x 64 rows = 256 rows, scans one candidate quarter (2048).
__global__ __launch_bounds__(TPB, 3) void chamfer_main_k(
    const uint4* __restrict__ afrag, const uint4* __restrict__ bfrag,
    float* __restrict__ gpart) {
  int t = threadIdx.x, lane = t & 63, w = t >> 6;    // 4 waves
  int b0 = blockIdx.x;
  // XCD-bijective swizzle (2048 blocks % 8 == 0): each XCD gets 256
  // consecutive effective ids = 2 full (dir,batch) families -> small L2 set.
  int eff = ((b0 & 7) << 8) | (b0 >> 3);
  int q = eff & 3;                 // candidate quarter (64 B-tiles)
  int rg = eff >> 2;               // 0..511 : 256-row groups
  int dir = rg >> 8;
  int batch = (rg >> 5) & 7;
  int rb = rg & 31;                // 256-row block within batch

  // A-frags: 2 row-tiles (64 rows) per wave, straight from prepacked global.
  int tileA0 = dir * NTILES + batch * 256 + rb * 8 + w * 2;
  bf16x8 A0 = __builtin_bit_cast(bf16x8, afrag[tileA0 * 64 + lane]);
  bf16x8 A1 = __builtin_bit_cast(bf16x8, afrag[(tileA0 + 1) * 64 + lane]);

  const uint4* bt = bfrag + (size_t)(dir * NTILES + batch * 256 + q * 64) * 64 + lane;

  f32x16 z, rm0, rm1;
#pragma unroll
  for (int r = 0; r < 16; ++r) { z[r] = 0.0f; rm0[r] = 1e30f; rm1[r] = 1e30f; }

#define LD(ti) __builtin_bit_cast(bf16x8, bt[(ti) * 64])
#define STEP(Bx, By)                                                        \
  do {                                                                      \
    f32x16 a0 = __builtin_amdgcn_mfma_f32_32x32x16_bf16(A0, Bx, z, 0, 0, 0);\
    f32x16 a1 = __builtin_amdgcn_mfma_f32_32x32x16_bf16(A1, Bx, z, 0, 0, 0);\
    f32x16 a2 = __builtin_amdgcn_mfma_f32_32x32x16_bf16(A0, By, z, 0, 0, 0);\
    f32x16 a3 = __builtin_amdgcn_mfma_f32_32x32x16_bf16(A1, By, z, 0, 0, 0);\
    _Pragma("unroll")                                                       \
    for (int r = 0; r < 16; ++r) {                                          \
      rm0[r] = fminf(fminf(rm0[r], a0[r]), a2[r]);   /* v_min3_f32 */       \
      rm1[r] = fminf(fminf(rm1[r], a1[r]), a3[r]);   /* v_min3_f32 */       \
    }                                                                       \
  } while (0)

  // software pipeline: B tiles loaded 2 steps (>=400cy) before use.
  bf16x8 b0v = LD(0), b1v = LD(1), b2v = LD(2), b3v = LD(3);
#pragma unroll 4
  for (int j = 0; j < 64; j += 4) {
    bf16x8 t0 = LD((j + 4) & 63), t1 = LD((j + 5) & 63);
    STEP(b0v, b1v);
    b0v = t0; b1v = t1;
    bf16x8 t2 = LD((j + 6) & 63), t3 = LD((j + 7) & 63);
    STEP(b2v, b3v);
    b2v = t2; b3v = t3;
  }
#undef LD
#undef STEP

  // ---- epilogue: fold 32 cols per half (butterfly), store row-mins ----
#pragma unroll
  for (int msk = 1; msk <= 16; msk <<= 1)
#pragma unroll
    for (int r = 0; r < 16; ++r) {
      rm0[r] = fminf(rm0[r], __shfl_xor(rm0[r], msk, 64));
      rm1[r] = fminf(rm1[r], __shfl_xor(rm1[r], msk, 64));
    }

  int rowbase = dir * PTS + batch * N_ + rb * 256 + w * 64;
  float* gp = gpart + q * ROWS_TOTAL + rowbase;
  if ((lane & 31) == 0) {                      // lanes 0 and 32 (h = lane>>5)
    int h = lane >> 5;
#pragma unroll
    for (int r = 0; r < 16; ++r) {
      int rr = (r & 3) + 8 * (r >> 2) + 4 * h;
      gp[rr] = rm0[r];
      gp[32 + rr] = rm1[r];
    }
  }
}

// ---- final: min the 4 candidate-quarter partials, sum everything ----
__global__ __launch_bounds__(256) void chamfer_final_k(
    const float* __restrict__ gpart, float* __restrict__ out) {
  int i = blockIdx.x * 256 + threadIdx.x;    // 32768 threads x 4 rows (float4)
  const float4* g4 = reinterpret_cast<const float4*>(gpart);
  float4 a = g4[i];
  float4 b = g4[i + (ROWS_TOTAL / 4)];
  float4 c = g4[i + 2 * (ROWS_TOTAL / 4)];
  float4 d = g4[i + 3 * (ROWS_TOTAL / 4)];
  float s = fminf(fminf(a.x, b.x), fminf(c.x, d.x))
          + fminf(fminf(a.y, b.y), fminf(c.y, d.y))
          + fminf(fminf(a.z, b.z), fminf(c.z, d.z))
          + fminf(fminf(a.w, b.w), fminf(c.w, d.w));
  for (int off = 32; off > 0; off >>= 1) s += __shfl_down(s, off, 64);
  __shared__ float red[4];
  int lane = threadIdx.x & 63, wv = threadIdx.x >> 6;
  if (lane == 0) red[wv] = s;
  __syncthreads();
  if (threadIdx.x == 0) {
    float tt = (red[0] + red[1]) + (red[2] + red[3]);
    atomicAdd(out, tt * (1.0f / (float)PTS));
  }
}

extern "C" void kernel_launch(void* const* d_in, const int* in_sizes, int n_in,
                              void* d_out, int out_size, void* d_ws, size_t ws_size,
                              hipStream_t stream) {
  const float* x = (const float*)d_in[0];
  const float* y = (const float*)d_in[1];
  float* out = (float*)d_out;
  // ws layout: gpart 2MB | afrag 4MB | bfrag 4MB  (10MB total)
  float* gpart = (float*)d_ws;
  uint4* afrag = (uint4*)((char*)d_ws + (size_t)4 * ROWS_TOTAL * sizeof(float));
  uint4* bfrag = afrag + (size_t)2 * NTILES * 64;

  hipMemsetAsync(out, 0, sizeof(float), stream);
  pack_frags_k<<<1024, 256, 0, stream>>>(x, y, afrag, bfrag);
  chamfer_main_k<<<2048, TPB, 0, stream>>>(afrag, bfrag, gpart);
  chamfer_final_k<<<128, 256, 0, stream>>>(gpart, out);
}